// Round 8
// baseline (492.658 us; speedup 1.0000x reference)
//
#include <hip/hip_runtime.h>
#include <hip/hip_bf16.h>
#include <stdint.h>

typedef float  f32x4  __attribute__((ext_vector_type(4)));
typedef short  bf16x8 __attribute__((ext_vector_type(8)));
typedef short  bf16x4 __attribute__((ext_vector_type(4)));
typedef unsigned short u16x8 __attribute__((ext_vector_type(8)));

#define MFMA16(a, b, c) __builtin_amdgcn_mfma_f32_16x16x32_bf16((a), (b), (c), 0, 0, 0)

// 16x16x16 bf16 MFMA: A/B = 4 bf16/lane (k = (lane>>4)*4 + reg), C/D standard 16x16.
#if __has_builtin(__builtin_amdgcn_mfma_f32_16x16x16bf16_1k)
#define MFMA16K16(a, b, c) __builtin_amdgcn_mfma_f32_16x16x16bf16_1k((a), (b), (c), 0, 0, 0)
#else
__device__ __forceinline__ f32x4 mfma16k16_asm(bf16x4 a, bf16x4 b, f32x4 c) {
  f32x4 d;
  asm volatile("v_mfma_f32_16x16x16_bf16 %0, %1, %2, %3"
               : "=v"(d) : "v"(a), "v"(b), "v"(c));
  return d;
}
#define MFMA16K16(a, b, c) mfma16k16_asm((a), (b), (c))
#endif

__device__ __forceinline__ void gload16(const void* g, void* l) {
  __builtin_amdgcn_global_load_lds((const __attribute__((address_space(1))) void*)g,
                                   (__attribute__((address_space(3))) void*)l,
                                   16, 0, 0);
}

__device__ __forceinline__ unsigned short bf16bits(float f) {
  __hip_bfloat16 h = __float2bfloat16(f);
  return *(unsigned short*)&h;
}

__device__ __forceinline__ float bf2f(unsigned short u) {
  unsigned int x = ((unsigned int)u) << 16;
  return *(float*)&x;
}

// LDS-only barrier: drains DS ops, leaves VMEM (vmcnt) in flight.
__device__ __forceinline__ void block_sync_lds() {
  asm volatile("s_waitcnt lgkmcnt(0)" ::: "memory");
  __builtin_amdgcn_s_barrier();
  asm volatile("" ::: "memory");
}

__device__ __forceinline__ void fence_order() { asm volatile("" ::: "memory"); }

// ---------------- fp32 -> bf16 cast, 4 elems/thread ----------------
__global__ void cast_kernel(const float* __restrict__ s, __hip_bfloat16* __restrict__ d, int n4) {
  int i = blockIdx.x * blockDim.x + threadIdx.x;
  if (i < n4) {
    float4 v = ((const float4*)s)[i];
    ushort4 u;
    u.x = bf16bits(v.x); u.y = bf16bits(v.y); u.z = bf16bits(v.z); u.w = bf16bits(v.w);
    ((ushort4*)d)[i] = u;
  }
}

// ---------------- GEMM1: qkv = xb @ wqkvb^T + b_qkv; scatter to Q,K,Vt (bf16) ----------------
__global__ __launch_bounds__(256) void gemm_qkv_kernel(
    const __hip_bfloat16* __restrict__ A,
    const __hip_bfloat16* __restrict__ B,
    const float* __restrict__ bias,
    __hip_bfloat16* __restrict__ Qo,
    __hip_bfloat16* __restrict__ Ko,
    __hip_bfloat16* __restrict__ Vt) {
  const int K = 1024;
  __shared__ __align__(16) __hip_bfloat16 As[128 * 32];
  __shared__ __align__(16) __hip_bfloat16 Bs[128 * 32];
  const int t = threadIdx.x;
  const int lane = t & 63, wv = t >> 6;
  const int wm = (wv >> 1) * 64, wn = (wv & 1) * 64;
  const int lr = lane & 15, lq = lane >> 4;
  const int m0 = blockIdx.y * 128, n0 = blockIdx.x * 128;

  f32x4 acc[4][4] = {};

  const int arow = t >> 2;
  const int acol = (t & 3) * 8;
  const __hip_bfloat16* Ag = A + (long)(m0 + arow) * K + acol;
  const __hip_bfloat16* Bg = B + (long)(n0 + arow) * K + acol;
  __hip_bfloat16* Asl = As + t * 8;
  __hip_bfloat16* Bsl = Bs + t * 8;

  for (int kk = 0; kk < K; kk += 32) {
    gload16(Ag + kk, Asl);
    gload16(Ag + kk + 64 * K, Asl + 2048);
    gload16(Bg + kk, Bsl);
    gload16(Bg + kk + 64 * K, Bsl + 2048);
    __syncthreads();
    bf16x8 af[4], bf[4];
#pragma unroll
    for (int i = 0; i < 4; ++i)
      af[i] = *(const bf16x8*)&As[(wm + i * 16 + lr) * 32 + lq * 8];
#pragma unroll
    for (int j = 0; j < 4; ++j)
      bf[j] = *(const bf16x8*)&Bs[(wn + j * 16 + lr) * 32 + lq * 8];
#pragma unroll
    for (int i = 0; i < 4; ++i)
#pragma unroll
      for (int j = 0; j < 4; ++j)
        acc[i][j] = MFMA16(af[i], bf[j], acc[i][j]);
    __syncthreads();
  }

#pragma unroll
  for (int i = 0; i < 4; ++i) {
#pragma unroll
    for (int j = 0; j < 4; ++j) {
      int col = n0 + wn + j * 16 + lr;
      int tsel = col >> 10, rem = col & 1023;
      int h = rem >> 6, d = rem & 63;
      float bs = bias[col];
      int rowb = m0 + wm + i * 16 + lq * 4;
#pragma unroll
      for (int r = 0; r < 4; ++r) {
        int m = rowb + r;
        int b = m >> 11, sdx = m & 2047;
        __hip_bfloat16 v = __float2bfloat16(acc[i][j][r] + bs);
        long bh = (long)(b * 16 + h);
        if (tsel == 0)       Qo[(bh * 2048 + sdx) * 64 + d] = v;
        else if (tsel == 1)  Ko[(bh * 2048 + sdx) * 64 + d] = v;
        else                 Vt[(bh * 64 + d) * 2048 + sdx] = v;
      }
    }
  }
}

// ---------------- fused attention v8: V direct, 2 barriers/iter, 2 blocks/CU ----------------
// r7 diagnosis: barrier/serialization-bound (MfmaUtil 13, VALU 22, occ 22,
// conflicts fixed). Key insight: PV reads NO LDS (P lane-local since v6), so
// after QK the K-buffer is fully consumed, and V's fragment (V^T[d][k..k+4])
// is a natural b64 GLOBAL load. v8:
//  (1) V direct-to-register (8 b64/wave/iter, issued at top, consumed at PV
//      ~1500cy later, L2-resident): kills V staging DMA + V LDS reads.
//  (2) LDS = K dbuf 64KB + psum 16KB = 81920 B -> 2 blocks/CU: TLP hides
//      barrier stalls (r5 proved TLP useless only when LDS-pipe-saturated;
//      now pipe ~25%). psum un-padded but lane-ROTATED: slot=(lq+lr)&3 --
//      one formula for writer/reducer/inv-reader, conflict-free.
//  (3) 2 barriers/iter: BAR1 (partials) and BAR2 (inv + K-DMA visibility;
//      vmcnt(0) moved before it). Buffer-switch barrier is unnecessary:
//      K-buf last read is QK, >=2 barriers before the overwriting stage.
__global__ __launch_bounds__(512, 4) void attn_kernel(
    const __hip_bfloat16* __restrict__ Q,
    const __hip_bfloat16* __restrict__ K,
    const __hip_bfloat16* __restrict__ Vt,
    __hip_bfloat16* __restrict__ part) {
  __shared__ __align__(16) __hip_bfloat16 KsA[16 * 16 * 64];  // 32 KB
  __shared__ __align__(16) __hip_bfloat16 KsB[16 * 16 * 64];  // 32 KB
  __shared__ __align__(16) float psum[2 * 8 * 16 * 16];       // 16 KB, lane-rotated

  const int t = threadIdx.x, lane = t & 63, wv = t >> 6;
  const int lr = lane & 15, lq = lane >> 4;
  const int h0 = wv * 2;  // this wave's two heads
  const int combo = blockIdx.x & 7;
  const int b = combo & 1, chunk = combo >> 1;
  const int q0 = (blockIdx.x >> 3) * 32;
  const int k0 = chunk * 512;
  const float c = 0.03125f * 1.44269504f;  // (1/sqrt(E)) * log2(e), E=1024
  const long bh16 = (long)(b * 16);
  const int rot = ((lq + lr) & 3) * 4;     // psum rotation slot (words)

  // K staging: row rho = h*16+kl (128B), 8 granules; LDS linear, swizzle on SOURCE.
  auto stageK = [&](__hip_bfloat16* dst, int kks) {
#pragma unroll
    for (int cc = 0; cc < 4; ++cc) {
      const int p = cc * 8192 + t * 16;
      const int rho = p >> 7;
      const int hh = rho >> 4, kl = rho & 15;
      const int g = ((p >> 4) & 7) ^ (rho & 7);
      const __hip_bfloat16* src = K + ((bh16 + hh) * 2048 + kks + kl) * 64 + g * 8;
      gload16(src, (char*)dst + p);
    }
    fence_order();
  };

  // Q fragments (B-operand of S^T): lane holds Q[q0+qt*16+lr][dh*32+lq*8..+8]
  bf16x8 qf[2][2][2];  // [hh][qt][dh]
#pragma unroll
  for (int hh = 0; hh < 2; ++hh)
#pragma unroll
    for (int qt = 0; qt < 2; ++qt)
#pragma unroll
      for (int dh = 0; dh < 2; ++dh)
        qf[hh][qt][dh] = *(const bf16x8*)(
            Q + ((bh16 + h0 + hh) * 2048 + q0 + qt * 16 + lr) * 64 + dh * 32 + lq * 8);

  stageK(KsA, k0);
  asm volatile("s_waitcnt vmcnt(0)" ::: "memory");
  block_sync_lds();

  f32x4 ctx[2][2][4] = {};  // [hh][qt][dt], lane: d = dt*16+lq*4+r, q = qt*16+lr

  auto body = [&](const __hip_bfloat16* Kc, __hip_bfloat16* Kn, int kt) {
    const int kk = k0 + kt * 16;
    // ---- V(kt) global loads FIRST (older than K-DMA -> never blocks on it) ----
    bf16x4 vg[2][4];
#pragma unroll
    for (int hh = 0; hh < 2; ++hh) {
      const __hip_bfloat16* vb = Vt + ((bh16 + h0 + hh) * 64 + lr) * 2048 + kk + lq * 4;
#pragma unroll
      for (int dt = 0; dt < 4; ++dt)
        vg[hh][dt] = *(const bf16x4*)(vb + (long)dt * 16 * 2048);
    }
    // ---- stage next K tile (WAR safe: Kn last read at QK(kt-1), 2 barriers ago) ----
    if (kt < 31) stageK(Kn, kk + 16);
    // ---- S^T = K·Q^T: 2 heads x 2 q-tiles, K frags shared across qt ----
    f32x4 s[2][2];
    __builtin_amdgcn_s_setprio(1);
#pragma unroll
    for (int hh = 0; hh < 2; ++hh) {
      const int rho = (h0 + hh) * 16 + lr;
      const __hip_bfloat16* kr = Kc + rho * 64;
      bf16x8 kf0 = *(const bf16x8*)(kr + ((lq ^ (rho & 7)) << 3));
      bf16x8 kf1 = *(const bf16x8*)(kr + (((lq + 4) ^ (rho & 7)) << 3));
#pragma unroll
      for (int qt = 0; qt < 2; ++qt) {
        f32x4 a = {};
        a = MFMA16(kf0, qf[hh][qt][0], a);
        a = MFMA16(kf1, qf[hh][qt][1], a);
        s[hh][qt] = a;
      }
    }
    __builtin_amdgcn_s_setprio(0);
    // ---- exp + per-wave 2-head partial sums (rotated slots) ----
#pragma unroll
    for (int qt = 0; qt < 2; ++qt) {
      f32x4 pp;
#pragma unroll
      for (int r = 0; r < 4; ++r) {
        s[0][qt][r] = __builtin_amdgcn_exp2f(s[0][qt][r] * c);
        s[1][qt][r] = __builtin_amdgcn_exp2f(s[1][qt][r] * c);
        pp[r] = s[0][qt][r] + s[1][qt][r];
      }
      *(f32x4*)&psum[qt * 2048 + wv * 256 + lr * 16 + rot] = pp;
    }
    block_sync_lds();  // BAR1: partials visible
    // ---- waves 0/1 reduce q-tiles 0/1; publish rcp into w=0 region ----
    if (wv < 2) {
      f32x4 tot = {};
#pragma unroll
      for (int w2 = 0; w2 < 8; ++w2)
        tot += *(const f32x4*)&psum[wv * 2048 + w2 * 256 + lr * 16 + rot];
      f32x4 inv;
#pragma unroll
      for (int r = 0; r < 4; ++r) inv[r] = __builtin_amdgcn_rcpf(tot[r]);
      *(f32x4*)&psum[wv * 2048 + lr * 16 + rot] = inv;  // w=0 slot, already consumed
    }
    // ---- drain K(kt+1) DMA + V(kt); BAR2 makes K visible AND inv visible ----
    asm volatile("s_waitcnt vmcnt(0)" ::: "memory");
    block_sync_lds();  // BAR2
    // ---- PV: p4 in registers; V pre-loaded in vg ----
    __builtin_amdgcn_s_setprio(1);
    f32x4 inv0 = *(const f32x4*)&psum[lr * 16 + rot];
    f32x4 inv1 = *(const f32x4*)&psum[2048 + lr * 16 + rot];
#pragma unroll
    for (int hh = 0; hh < 2; ++hh) {
#pragma unroll
      for (int qt = 0; qt < 2; ++qt) {
        const f32x4 iv = qt ? inv1 : inv0;
        bf16x4 p4;
#pragma unroll
        for (int r = 0; r < 4; ++r) p4[r] = (short)bf16bits(s[hh][qt][r] * iv[r]);
#pragma unroll
        for (int dt = 0; dt < 4; ++dt)
          ctx[hh][qt][dt] = MFMA16K16(vg[hh][dt], p4, ctx[hh][qt][dt]);
      }
    }
    __builtin_amdgcn_s_setprio(0);
    // no trailing barrier: PV touches no LDS; next iter's stage target was
    // last read >= 2 barriers ago.
  };

#pragma unroll 1
  for (int kp = 0; kp < 16; ++kp) {
    body(KsA, KsB, 2 * kp);
    body(KsB, KsA, 2 * kp + 1);
  }

  // ---- epilogue: per q-tile, ctx^T -> LDS (reuse KsA) -> coalesced store ----
  // Safe: KsA last read at QK(kt=30), >=2 barriers ago; PV is register-only.
  unsigned short* Pc = (unsigned short*)KsA;
#pragma unroll
  for (int qt = 0; qt < 2; ++qt) {
    if (qt) block_sync_lds();  // pass-0 reads done before overwrite
#pragma unroll
    for (int hh = 0; hh < 2; ++hh) {
      const int h = h0 + hh;
#pragma unroll
      for (int dt = 0; dt < 4; ++dt) {
        bf16x4 pk;
#pragma unroll
        for (int r = 0; r < 4; ++r) pk[r] = (short)bf16bits(ctx[hh][qt][dt][r]);
        const int o = h * 128 + dt * 32 + lq * 8;  // byte off in hd-row (d=dt*16+lq*4+r)
        *(bf16x4*)((char*)Pc + lr * 2048 + (o ^ ((lr & 7) << 4))) = pk;
      }
    }
    block_sync_lds();
    unsigned short* gbase = (unsigned short*)part +
        ((long)(chunk * 4096 + b * 2048 + q0 + qt * 16)) * 1024;
#pragma unroll
    for (int j = 0; j < 4; ++j) {
      int gf = (j * 512 + t) * 8;  // flat over [16q][16h*64d]
      int q = gf >> 10, hd = gf & 1023;
      u16x8 v = *(const u16x8*)((char*)Pc + q * 2048 + ((hd * 2) ^ ((q & 7) << 4)));
      *(u16x8*)&gbase[gf] = v;
    }
  }
}

// ---------------- reduce 4 bf16 chunk partials + cast to bf16 ----------------
__global__ void reduce_cast_kernel(const unsigned short* __restrict__ part,
                                   __hip_bfloat16* __restrict__ dst) {
  int i = blockIdx.x * blockDim.x + threadIdx.x;  // 1M threads, 4 elems each
  const long S4 = (long)4096 * 1024 / 4;          // ushort4 units per chunk
  const ushort4* p = (const ushort4*)part;
  float sx = 0.f, sy = 0.f, sz = 0.f, sw = 0.f;
#pragma unroll
  for (int c = 0; c < 4; ++c) {
    ushort4 v = p[i + c * S4];
    sx += bf2f(v.x); sy += bf2f(v.y); sz += bf2f(v.z); sw += bf2f(v.w);
  }
  ushort4 u;
  u.x = bf16bits(sx); u.y = bf16bits(sy); u.z = bf16bits(sz); u.w = bf16bits(sw);
  ((ushort4*)dst)[i] = u;
}

// ---------------- GEMM2: out = ctxb @ woutb^T + b_out (fp32 out) ----------------
__global__ __launch_bounds__(256) void gemm_out_kernel(
    const __hip_bfloat16* __restrict__ A,   // [4096][1024]
    const __hip_bfloat16* __restrict__ B,   // [1024][1024]
    const float* __restrict__ bias,
    float* __restrict__ out) {
  const int K = 1024;
  __shared__ __align__(16) __hip_bfloat16 As[128 * 32];
  __shared__ __align__(16) __hip_bfloat16 Bs[128 * 32];
  const int t = threadIdx.x;
  const int lane = t & 63, wv = t >> 6;
  const int wm = (wv >> 1) * 64, wn = (wv & 1) * 64;
  const int lr = lane & 15, lq = lane >> 4;
  const int m0 = blockIdx.y * 128, n0 = blockIdx.x * 128;

  f32x4 acc[4][4] = {};

  const int arow = t >> 2;
  const int acol = (t & 3) * 8;
  const __hip_bfloat16* Ag = A + (long)(m0 + arow) * K + acol;
  const __hip_bfloat16* Bg = B + (long)(n0 + arow) * K + acol;
  __hip_bfloat16* Asl = As + t * 8;
  __hip_bfloat16* Bsl = Bs + t * 8;

  for (int kk = 0; kk < K; kk += 32) {
    gload16(Ag + kk, Asl);
    gload16(Ag + kk + 64 * K, Asl + 2048);
    gload16(Bg + kk, Bsl);
    gload16(Bg + kk + 64 * K, Bsl + 2048);
    __syncthreads();
    bf16x8 af[4], bf[4];
#pragma unroll
    for (int i = 0; i < 4; ++i)
      af[i] = *(const bf16x8*)&As[(wm + i * 16 + lr) * 32 + lq * 8];
#pragma unroll
    for (int j = 0; j < 4; ++j)
      bf[j] = *(const bf16x8*)&Bs[(wn + j * 16 + lr) * 32 + lq * 8];
#pragma unroll
    for (int i = 0; i < 4; ++i)
#pragma unroll
      for (int j = 0; j < 4; ++j)
        acc[i][j] = MFMA16(af[i], bf[j], acc[i][j]);
    __syncthreads();
  }

#pragma unroll
  for (int i = 0; i < 4; ++i) {
#pragma unroll
    for (int j = 0; j < 4; ++j) {
      int col = n0 + wn + j * 16 + lr;
      float bs = bias[col];
      int rowb = m0 + wm + i * 16 + lq * 4;
#pragma unroll
      for (int r = 0; r < 4; ++r) {
        out[(long)(rowb + r) * 1024 + col] = acc[i][j][r] + bs;
      }
    }
  }
}

extern "C" void kernel_launch(void* const* d_in, const int* in_sizes, int n_in,
                              void* d_out, int out_size, void* d_ws, size_t ws_size,
                              hipStream_t stream) {
  const float* x     = (const float*)d_in[0];
  const float* w_qkv = (const float*)d_in[1];
  const float* b_qkv = (const float*)d_in[2];
  const float* w_out = (const float*)d_in[3];
  const float* b_out = (const float*)d_in[4];
  float* out = (float*)d_out;
  char* ws = (char*)d_ws;

  // workspace layout (80 MB total)
  __hip_bfloat16* xb    = (__hip_bfloat16*)(ws);                       // 8 MB
  __hip_bfloat16* wqkvb = (__hip_bfloat16*)(ws + (8ul << 20));         // 6 MB
  __hip_bfloat16* woutb = (__hip_bfloat16*)(ws + (14ul << 20));        // 2 MB
  __hip_bfloat16* Qb    = (__hip_bfloat16*)(ws + (16ul << 20));        // 8 MB
  __hip_bfloat16* Kb    = (__hip_bfloat16*)(ws + (24ul << 20));        // 8 MB
  __hip_bfloat16* Vtb   = (__hip_bfloat16*)(ws + (32ul << 20));        // 8 MB
  __hip_bfloat16* partb = (__hip_bfloat16*)(ws + (40ul << 20));        // 32 MB (4 bf16 chunks)
  __hip_bfloat16* ctxb  = (__hip_bfloat16*)(ws + (72ul << 20));        // 8 MB

  cast_kernel<<<4096, 256, 0, stream>>>(x, xb, 4194304 / 4);
  cast_kernel<<<3072, 256, 0, stream>>>(w_qkv, wqkvb, 3145728 / 4);
  cast_kernel<<<1024, 256, 0, stream>>>(w_out, woutb, 1048576 / 4);
  gemm_qkv_kernel<<<dim3(24, 32), 256, 0, stream>>>(xb, wqkvb, b_qkv, Qb, Kb, Vtb);
  attn_kernel<<<512, 512, 0, stream>>>(Qb, Kb, Vtb, partb);
  reduce_cast_kernel<<<4096, 256, 0, stream>>>((const unsigned short*)partb, ctxb);
  gemm_out_kernel<<<dim3(8, 32), 256, 0, stream>>>(ctxb, woutb, b_out, out);
}

// Round 9
// 268.619 us; speedup vs baseline: 1.8340x; 1.8340x over previous
//
#include <hip/hip_runtime.h>
#include <hip/hip_bf16.h>
#include <stdint.h>

typedef float  f32x4  __attribute__((ext_vector_type(4)));
typedef short  bf16x8 __attribute__((ext_vector_type(8)));
typedef short  bf16x4 __attribute__((ext_vector_type(4)));
typedef unsigned short u16x8 __attribute__((ext_vector_type(8)));

#define MFMA16(a, b, c) __builtin_amdgcn_mfma_f32_16x16x32_bf16((a), (b), (c), 0, 0, 0)

// 16x16x16 bf16 MFMA: A/B = 4 bf16/lane (k = (lane>>4)*4 + reg), C/D standard 16x16.
#if __has_builtin(__builtin_amdgcn_mfma_f32_16x16x16bf16_1k)
#define MFMA16K16(a, b, c) __builtin_amdgcn_mfma_f32_16x16x16bf16_1k((a), (b), (c), 0, 0, 0)
#else
__device__ __forceinline__ f32x4 mfma16k16_asm(bf16x4 a, bf16x4 b, f32x4 c) {
  f32x4 d;
  asm volatile("v_mfma_f32_16x16x16_bf16 %0, %1, %2, %3"
               : "=v"(d) : "v"(a), "v"(b), "v"(c));
  return d;
}
#define MFMA16K16(a, b, c) mfma16k16_asm((a), (b), (c))
#endif

__device__ __forceinline__ void gload16(const void* g, void* l) {
  __builtin_amdgcn_global_load_lds((const __attribute__((address_space(1))) void*)g,
                                   (__attribute__((address_space(3))) void*)l,
                                   16, 0, 0);
}

__device__ __forceinline__ unsigned short bf16bits(float f) {
  __hip_bfloat16 h = __float2bfloat16(f);
  return *(unsigned short*)&h;
}

__device__ __forceinline__ float bf2f(unsigned short u) {
  unsigned int x = ((unsigned int)u) << 16;
  return *(float*)&x;
}

// LDS-only barrier: drains DS ops, leaves VMEM (vmcnt) in flight.
__device__ __forceinline__ void block_sync_lds() {
  asm volatile("s_waitcnt lgkmcnt(0)" ::: "memory");
  __builtin_amdgcn_s_barrier();
  asm volatile("" ::: "memory");
}

__device__ __forceinline__ void fence_order() { asm volatile("" ::: "memory"); }

// ---------------- fp32 -> bf16 cast, 4 elems/thread ----------------
__global__ void cast_kernel(const float* __restrict__ s, __hip_bfloat16* __restrict__ d, int n4) {
  int i = blockIdx.x * blockDim.x + threadIdx.x;
  if (i < n4) {
    float4 v = ((const float4*)s)[i];
    ushort4 u;
    u.x = bf16bits(v.x); u.y = bf16bits(v.y); u.z = bf16bits(v.z); u.w = bf16bits(v.w);
    ((ushort4*)d)[i] = u;
  }
}

// ---------------- GEMM1: qkv = xb @ wqkvb^T + b_qkv; scatter to Q,K,Vtile (bf16) ----------------
// V layout (v9): Vt[bh][kb=s/16][d=64][ki=16] -- a wave's PV fragment (16 d-rows
// x 4 ki each, 8 B/lane) covers 512 CONTIGUOUS bytes -> fully coalesced direct
// global loads in attn (r8's 4KB-stride pattern caused ~8x line overfetch).
__global__ __launch_bounds__(256) void gemm_qkv_kernel(
    const __hip_bfloat16* __restrict__ A,
    const __hip_bfloat16* __restrict__ B,
    const float* __restrict__ bias,
    __hip_bfloat16* __restrict__ Qo,
    __hip_bfloat16* __restrict__ Ko,
    __hip_bfloat16* __restrict__ Vt) {
  const int K = 1024;
  __shared__ __align__(16) __hip_bfloat16 As[128 * 32];
  __shared__ __align__(16) __hip_bfloat16 Bs[128 * 32];
  const int t = threadIdx.x;
  const int lane = t & 63, wv = t >> 6;
  const int wm = (wv >> 1) * 64, wn = (wv & 1) * 64;
  const int lr = lane & 15, lq = lane >> 4;
  const int m0 = blockIdx.y * 128, n0 = blockIdx.x * 128;

  f32x4 acc[4][4] = {};

  const int arow = t >> 2;
  const int acol = (t & 3) * 8;
  const __hip_bfloat16* Ag = A + (long)(m0 + arow) * K + acol;
  const __hip_bfloat16* Bg = B + (long)(n0 + arow) * K + acol;
  __hip_bfloat16* Asl = As + t * 8;
  __hip_bfloat16* Bsl = Bs + t * 8;

  for (int kk = 0; kk < K; kk += 32) {
    gload16(Ag + kk, Asl);
    gload16(Ag + kk + 64 * K, Asl + 2048);
    gload16(Bg + kk, Bsl);
    gload16(Bg + kk + 64 * K, Bsl + 2048);
    __syncthreads();
    bf16x8 af[4], bf[4];
#pragma unroll
    for (int i = 0; i < 4; ++i)
      af[i] = *(const bf16x8*)&As[(wm + i * 16 + lr) * 32 + lq * 8];
#pragma unroll
    for (int j = 0; j < 4; ++j)
      bf[j] = *(const bf16x8*)&Bs[(wn + j * 16 + lr) * 32 + lq * 8];
#pragma unroll
    for (int i = 0; i < 4; ++i)
#pragma unroll
      for (int j = 0; j < 4; ++j)
        acc[i][j] = MFMA16(af[i], bf[j], acc[i][j]);
    __syncthreads();
  }

#pragma unroll
  for (int i = 0; i < 4; ++i) {
#pragma unroll
    for (int j = 0; j < 4; ++j) {
      int col = n0 + wn + j * 16 + lr;
      int tsel = col >> 10, rem = col & 1023;
      int h = rem >> 6, d = rem & 63;
      float bs = bias[col];
      int rowb = m0 + wm + i * 16 + lq * 4;
#pragma unroll
      for (int r = 0; r < 4; ++r) {
        int m = rowb + r;
        int b = m >> 11, sdx = m & 2047;
        __hip_bfloat16 v = __float2bfloat16(acc[i][j][r] + bs);
        long bh = (long)(b * 16 + h);
        if (tsel == 0)       Qo[(bh * 2048 + sdx) * 64 + d] = v;
        else if (tsel == 1)  Ko[(bh * 2048 + sdx) * 64 + d] = v;
        else                 Vt[((bh * 128 + (sdx >> 4)) * 64 + d) * 16 + (sdx & 15)] = v;
      }
    }
  }
}

// ---------------- fused attention v9: r8 structure, spill + V-coalescing fixed ----------------
// r8 post-mortem: __launch_bounds__(512,4) made the allocator target 64 VGPRs
// -> accumulator spills -> 706 MB FETCH / 146 MB WRITE scratch traffic.
// v9 = r8 with:
//  (1) __launch_bounds__(512,2): r7-proven allocator behavior (~104 VGPR),
//      under the 128 threshold, so LDS 81920 B still yields 2 blocks/CU.
//  (2) V tiled global layout [bh][kb][64d][16ki]: direct-to-register V loads
//      are 512 B contiguous per wave-fragment (was 8 B x 4 KB stride).
// Structure: K dbuf via global_load_lds (32+32 KB) + rotated psum 16 KB;
// 2 barriers/iter (PV reads no LDS; P lane-local; V in registers).
__global__ __launch_bounds__(512, 2) void attn_kernel(
    const __hip_bfloat16* __restrict__ Q,
    const __hip_bfloat16* __restrict__ K,
    const __hip_bfloat16* __restrict__ Vt,
    __hip_bfloat16* __restrict__ part) {
  __shared__ __align__(16) __hip_bfloat16 KsA[16 * 16 * 64];  // 32 KB
  __shared__ __align__(16) __hip_bfloat16 KsB[16 * 16 * 64];  // 32 KB
  __shared__ __align__(16) float psum[2 * 8 * 16 * 16];       // 16 KB, lane-rotated

  const int t = threadIdx.x, lane = t & 63, wv = t >> 6;
  const int lr = lane & 15, lq = lane >> 4;
  const int h0 = wv * 2;  // this wave's two heads
  const int combo = blockIdx.x & 7;
  const int b = combo & 1, chunk = combo >> 1;
  const int q0 = (blockIdx.x >> 3) * 32;
  const int k0 = chunk * 512;
  const float c = 0.03125f * 1.44269504f;  // (1/sqrt(E)) * log2(e), E=1024
  const long bh16 = (long)(b * 16);
  const int rot = ((lq + lr) & 3) * 4;     // psum rotation slot (words)

  // K staging: row rho = h*16+kl (128B), 8 granules; LDS linear, swizzle on SOURCE.
  auto stageK = [&](__hip_bfloat16* dst, int kks) {
#pragma unroll
    for (int cc = 0; cc < 4; ++cc) {
      const int p = cc * 8192 + t * 16;
      const int rho = p >> 7;
      const int hh = rho >> 4, kl = rho & 15;
      const int g = ((p >> 4) & 7) ^ (rho & 7);
      const __hip_bfloat16* src = K + ((bh16 + hh) * 2048 + kks + kl) * 64 + g * 8;
      gload16(src, (char*)dst + p);
    }
    fence_order();
  };

  // Q fragments (B-operand of S^T): lane holds Q[q0+qt*16+lr][dh*32+lq*8..+8]
  bf16x8 qf[2][2][2];  // [hh][qt][dh]
#pragma unroll
  for (int hh = 0; hh < 2; ++hh)
#pragma unroll
    for (int qt = 0; qt < 2; ++qt)
#pragma unroll
      for (int dh = 0; dh < 2; ++dh)
        qf[hh][qt][dh] = *(const bf16x8*)(
            Q + ((bh16 + h0 + hh) * 2048 + q0 + qt * 16 + lr) * 64 + dh * 32 + lq * 8);

  stageK(KsA, k0);
  asm volatile("s_waitcnt vmcnt(0)" ::: "memory");
  block_sync_lds();

  f32x4 ctx[2][2][4] = {};  // [hh][qt][dt], lane: d = dt*16+lq*4+r, q = qt*16+lr

  auto body = [&](const __hip_bfloat16* Kc, __hip_bfloat16* Kn, int kt) {
    const int kb = chunk * 32 + kt;  // V k-block index
    // ---- V(kt) coalesced global loads FIRST: 512 B contiguous per fragment ----
    bf16x4 vg[2][4];
#pragma unroll
    for (int hh = 0; hh < 2; ++hh) {
      const __hip_bfloat16* vb = Vt + ((bh16 + h0 + hh) * 128 + kb) * 1024;
#pragma unroll
      for (int dt = 0; dt < 4; ++dt)
        vg[hh][dt] = *(const bf16x4*)(vb + (dt * 16 + lr) * 16 + lq * 4);
    }
    // ---- stage next K tile (WAR safe: Kn last read at QK(kt-1), 2 barriers ago) ----
    if (kt < 31) stageK(Kn, k0 + kt * 16 + 16);
    // ---- S^T = K·Q^T: 2 heads x 2 q-tiles, K frags shared across qt ----
    f32x4 s[2][2];
    __builtin_amdgcn_s_setprio(1);
#pragma unroll
    for (int hh = 0; hh < 2; ++hh) {
      const int rho = (h0 + hh) * 16 + lr;
      const __hip_bfloat16* kr = Kc + rho * 64;
      bf16x8 kf0 = *(const bf16x8*)(kr + ((lq ^ (rho & 7)) << 3));
      bf16x8 kf1 = *(const bf16x8*)(kr + (((lq + 4) ^ (rho & 7)) << 3));
#pragma unroll
      for (int qt = 0; qt < 2; ++qt) {
        f32x4 a = {};
        a = MFMA16(kf0, qf[hh][qt][0], a);
        a = MFMA16(kf1, qf[hh][qt][1], a);
        s[hh][qt] = a;
      }
    }
    __builtin_amdgcn_s_setprio(0);
    // ---- exp + per-wave 2-head partial sums (rotated slots) ----
#pragma unroll
    for (int qt = 0; qt < 2; ++qt) {
      f32x4 pp;
#pragma unroll
      for (int r = 0; r < 4; ++r) {
        s[0][qt][r] = __builtin_amdgcn_exp2f(s[0][qt][r] * c);
        s[1][qt][r] = __builtin_amdgcn_exp2f(s[1][qt][r] * c);
        pp[r] = s[0][qt][r] + s[1][qt][r];
      }
      *(f32x4*)&psum[qt * 2048 + wv * 256 + lr * 16 + rot] = pp;
    }
    block_sync_lds();  // BAR1: partials visible
    // ---- waves 0/1 reduce q-tiles 0/1; publish rcp into w=0 region ----
    if (wv < 2) {
      f32x4 tot = {};
#pragma unroll
      for (int w2 = 0; w2 < 8; ++w2)
        tot += *(const f32x4*)&psum[wv * 2048 + w2 * 256 + lr * 16 + rot];
      f32x4 inv;
#pragma unroll
      for (int r = 0; r < 4; ++r) inv[r] = __builtin_amdgcn_rcpf(tot[r]);
      *(f32x4*)&psum[wv * 2048 + lr * 16 + rot] = inv;  // w=0 slot, already consumed
    }
    // ---- drain K(kt+1) DMA + V(kt); BAR2 makes K visible AND inv visible ----
    asm volatile("s_waitcnt vmcnt(0)" ::: "memory");
    block_sync_lds();  // BAR2
    // ---- PV: p4 in registers; V pre-loaded in vg ----
    __builtin_amdgcn_s_setprio(1);
    f32x4 inv0 = *(const f32x4*)&psum[lr * 16 + rot];
    f32x4 inv1 = *(const f32x4*)&psum[2048 + lr * 16 + rot];
#pragma unroll
    for (int hh = 0; hh < 2; ++hh) {
#pragma unroll
      for (int qt = 0; qt < 2; ++qt) {
        const f32x4 iv = qt ? inv1 : inv0;
        bf16x4 p4;
#pragma unroll
        for (int r = 0; r < 4; ++r) p4[r] = (short)bf16bits(s[hh][qt][r] * iv[r]);
#pragma unroll
        for (int dt = 0; dt < 4; ++dt)
          ctx[hh][qt][dt] = MFMA16K16(vg[hh][dt], p4, ctx[hh][qt][dt]);
      }
    }
    __builtin_amdgcn_s_setprio(0);
    // no trailing barrier: PV touches no LDS; next iter's stage target was
    // last read >= 2 barriers ago.
  };

#pragma unroll 1
  for (int kp = 0; kp < 16; ++kp) {
    body(KsA, KsB, 2 * kp);
    body(KsB, KsA, 2 * kp + 1);
  }

  // ---- epilogue: per q-tile, ctx^T -> LDS (reuse KsA) -> coalesced store ----
  // Safe: KsA last read at QK(kt=30), >=2 barriers ago; PV is register-only.
  unsigned short* Pc = (unsigned short*)KsA;
#pragma unroll
  for (int qt = 0; qt < 2; ++qt) {
    if (qt) block_sync_lds();  // pass-0 reads done before overwrite
#pragma unroll
    for (int hh = 0; hh < 2; ++hh) {
      const int h = h0 + hh;
#pragma unroll
      for (int dt = 0; dt < 4; ++dt) {
        bf16x4 pk;
#pragma unroll
        for (int r = 0; r < 4; ++r) pk[r] = (short)bf16bits(ctx[hh][qt][dt][r]);
        const int o = h * 128 + dt * 32 + lq * 8;  // byte off in hd-row (d=dt*16+lq*4+r)
        *(bf16x4*)((char*)Pc + lr * 2048 + (o ^ ((lr & 7) << 4))) = pk;
      }
    }
    block_sync_lds();
    unsigned short* gbase = (unsigned short*)part +
        ((long)(chunk * 4096 + b * 2048 + q0 + qt * 16)) * 1024;
#pragma unroll
    for (int j = 0; j < 4; ++j) {
      int gf = (j * 512 + t) * 8;  // flat over [16q][16h*64d]
      int q = gf >> 10, hd = gf & 1023;
      u16x8 v = *(const u16x8*)((char*)Pc + q * 2048 + ((hd * 2) ^ ((q & 7) << 4)));
      *(u16x8*)&gbase[gf] = v;
    }
  }
}

// ---------------- reduce 4 bf16 chunk partials + cast to bf16 ----------------
__global__ void reduce_cast_kernel(const unsigned short* __restrict__ part,
                                   __hip_bfloat16* __restrict__ dst) {
  int i = blockIdx.x * blockDim.x + threadIdx.x;  // 1M threads, 4 elems each
  const long S4 = (long)4096 * 1024 / 4;          // ushort4 units per chunk
  const ushort4* p = (const ushort4*)part;
  float sx = 0.f, sy = 0.f, sz = 0.f, sw = 0.f;
#pragma unroll
  for (int c = 0; c < 4; ++c) {
    ushort4 v = p[i + c * S4];
    sx += bf2f(v.x); sy += bf2f(v.y); sz += bf2f(v.z); sw += bf2f(v.w);
  }
  ushort4 u;
  u.x = bf16bits(sx); u.y = bf16bits(sy); u.z = bf16bits(sz); u.w = bf16bits(sw);
  ((ushort4*)dst)[i] = u;
}

// ---------------- GEMM2: out = ctxb @ woutb^T + b_out (fp32 out) ----------------
__global__ __launch_bounds__(256) void gemm_out_kernel(
    const __hip_bfloat16* __restrict__ A,   // [4096][1024]
    const __hip_bfloat16* __restrict__ B,   // [1024][1024]
    const float* __restrict__ bias,
    float* __restrict__ out) {
  const int K = 1024;
  __shared__ __align__(16) __hip_bfloat16 As[128 * 32];
  __shared__ __align__(16) __hip_bfloat16 Bs[128 * 32];
  const int t = threadIdx.x;
  const int lane = t & 63, wv = t >> 6;
  const int wm = (wv >> 1) * 64, wn = (wv & 1) * 64;
  const int lr = lane & 15, lq = lane >> 4;
  const int m0 = blockIdx.y * 128, n0 = blockIdx.x * 128;

  f32x4 acc[4][4] = {};

  const int arow = t >> 2;
  const int acol = (t & 3) * 8;
  const __hip_bfloat16* Ag = A + (long)(m0 + arow) * K + acol;
  const __hip_bfloat16* Bg = B + (long)(n0 + arow) * K + acol;
  __hip_bfloat16* Asl = As + t * 8;
  __hip_bfloat16* Bsl = Bs + t * 8;

  for (int kk = 0; kk < K; kk += 32) {
    gload16(Ag + kk, Asl);
    gload16(Ag + kk + 64 * K, Asl + 2048);
    gload16(Bg + kk, Bsl);
    gload16(Bg + kk + 64 * K, Bsl + 2048);
    __syncthreads();
    bf16x8 af[4], bf[4];
#pragma unroll
    for (int i = 0; i < 4; ++i)
      af[i] = *(const bf16x8*)&As[(wm + i * 16 + lr) * 32 + lq * 8];
#pragma unroll
    for (int j = 0; j < 4; ++j)
      bf[j] = *(const bf16x8*)&Bs[(wn + j * 16 + lr) * 32 + lq * 8];
#pragma unroll
    for (int i = 0; i < 4; ++i)
#pragma unroll
      for (int j = 0; j < 4; ++j)
        acc[i][j] = MFMA16(af[i], bf[j], acc[i][j]);
    __syncthreads();
  }

#pragma unroll
  for (int i = 0; i < 4; ++i) {
#pragma unroll
    for (int j = 0; j < 4; ++j) {
      int col = n0 + wn + j * 16 + lr;
      float bs = bias[col];
      int rowb = m0 + wm + i * 16 + lq * 4;
#pragma unroll
      for (int r = 0; r < 4; ++r) {
        out[(long)(rowb + r) * 1024 + col] = acc[i][j][r] + bs;
      }
    }
  }
}

extern "C" void kernel_launch(void* const* d_in, const int* in_sizes, int n_in,
                              void* d_out, int out_size, void* d_ws, size_t ws_size,
                              hipStream_t stream) {
  const float* x     = (const float*)d_in[0];
  const float* w_qkv = (const float*)d_in[1];
  const float* b_qkv = (const float*)d_in[2];
  const float* w_out = (const float*)d_in[3];
  const float* b_out = (const float*)d_in[4];
  float* out = (float*)d_out;
  char* ws = (char*)d_ws;

  // workspace layout (80 MB total)
  __hip_bfloat16* xb    = (__hip_bfloat16*)(ws);                       // 8 MB
  __hip_bfloat16* wqkvb = (__hip_bfloat16*)(ws + (8ul << 20));         // 6 MB
  __hip_bfloat16* woutb = (__hip_bfloat16*)(ws + (14ul << 20));        // 2 MB
  __hip_bfloat16* Qb    = (__hip_bfloat16*)(ws + (16ul << 20));        // 8 MB
  __hip_bfloat16* Kb    = (__hip_bfloat16*)(ws + (24ul << 20));        // 8 MB
  __hip_bfloat16* Vtb   = (__hip_bfloat16*)(ws + (32ul << 20));        // 8 MB
  __hip_bfloat16* partb = (__hip_bfloat16*)(ws + (40ul << 20));        // 32 MB (4 bf16 chunks)
  __hip_bfloat16* ctxb  = (__hip_bfloat16*)(ws + (72ul << 20));        // 8 MB

  cast_kernel<<<4096, 256, 0, stream>>>(x, xb, 4194304 / 4);
  cast_kernel<<<3072, 256, 0, stream>>>(w_qkv, wqkvb, 3145728 / 4);
  cast_kernel<<<1024, 256, 0, stream>>>(w_out, woutb, 1048576 / 4);
  gemm_qkv_kernel<<<dim3(24, 32), 256, 0, stream>>>(xb, wqkvb, b_qkv, Qb, Kb, Vtb);
  attn_kernel<<<512, 512, 0, stream>>>(Qb, Kb, Vtb, partb);
  reduce_cast_kernel<<<4096, 256, 0, stream>>>((const unsigned short*)partb, ctxb);
  gemm_out_kernel<<<dim3(8, 32), 256, 0, stream>>>(ctxb, woutb, b_out, out);
}